// Round 12
// baseline (722.021 us; speedup 1.0000x reference)
//
#include <hip/hip_runtime.h>

typedef unsigned short u16;
typedef unsigned int u32;
typedef float f32x4 __attribute__((ext_vector_type(4)));
typedef short s16x8 __attribute__((ext_vector_type(8)));

#define B_ 8
#define C_ 1024
#define N_ 4096
#define FD_ 128
#define P_ 2048
#define LOG2E 1.4426950408889634f

__device__ __forceinline__ u16 f2bf(float f) {
  u32 u = __float_as_uint(f);
  u32 r = (u + 0x7fffu + ((u >> 16) & 1u)) >> 16;
  return (u16)r;
}
__device__ __forceinline__ u32 pkbf(float a, float b) {  // {lo:bf16(a), hi:bf16(b)}
  u32 r;
  asm("v_cvt_pk_bf16_f32 %0, %1, %2" : "=v"(r) : "v"(a), "v"(b));
  return r;
}
__device__ __forceinline__ float lo16(u32 u) { return __uint_as_float(u << 16); }
__device__ __forceinline__ float hi16(u32 u) { return __uint_as_float(u & 0xffff0000u); }
__device__ __forceinline__ float bf2f(u16 u) { return __uint_as_float(((u32)u) << 16); }

#define AS1 __attribute__((address_space(1)))
#define AS3 __attribute__((address_space(3)))
__device__ __forceinline__ void gl16(const void* g, void* l) {
  __builtin_amdgcn_global_load_lds((AS1 const u32*)g, (AS3 u32*)l, 16, 0, 0);
}

// key permutation within a 32-key tile: V column c holds key tau32(c), so the
// S^T accumulator registers pack directly into the PV B-fragment (no shfl).
__device__ __forceinline__ int tau32(int c) {
  return ((c & 4) << 2) + ((c & 24) >> 1) + (c & 3);
}

// ============================ prep: fp32 -> bf16 weights / pool layouts =====
// wcatf fragment-linear layout so each proj LOADB reads one contiguous 1KB.
__global__ __launch_bounds__(256) void prep_kernel(
    const float* __restrict__ wth, const float* __restrict__ wph,
    const float* __restrict__ wg, const float* __restrict__ wo,
    const float* __restrict__ pool,
    u16* __restrict__ wcat, u16* __restrict__ wo_bf,
    u16* __restrict__ pool_k, u16* __restrict__ pool_vt) {
  int idx = blockIdx.x * 256 + threadIdx.x;
  if (idx < 393216) {                       // wcatf[3][16][2][8][16][4][8]
    int o = idx;
    int e = o & 7, hi2 = (o >> 3) & 3, lo2 = (o >> 5) & 15;
    int ft = (o >> 9) & 7, ks = (o >> 12) & 1, kk2 = (o >> 13) & 15;
    int y = o >> 17;
    int c = kk2 * 64 + ks * 32 + hi2 * 8 + e;
    int fj = y * 128 + ft * 16 + lo2;
    float v = (fj < 128) ? wth[fj * 1024 + c]
              : (fj < 256 ? wph[(fj - 128) * 1024 + c]
                          : wg[(fj - 256) * 1024 + c]);
    wcat[idx] = f2bf(v);
  } else if (idx < 524288) {                // wo_bf[1024][128]
    int i = idx - 393216;
    wo_bf[i] = f2bf(wo[i]);
  } else if (idx < 786432) {                // pool_k[2048][128] = pool^T
    int i = idx - 524288;
    int p = i >> 7, f = i & 127;
    pool_k[i] = f2bf(pool[f * 2048 + p]);
  } else if (idx < 1048576) {               // pool_vt[64 tiles][4 ch][128 f][8k]
    int j = idx - 786432;
    int tile = j >> 12, r = j & 4095;
    int ch = r >> 10, f = (r >> 3) & 127, kk = r & 7;
    pool_vt[j] = f2bf(pool[f * 2048 + tile * 32 + tau32(ch * 8 + kk)]);
  }
}

// ============================ proj: pipelined GEMM ==========================
// 768 blocks; XCD-partner decode (3 y-slices of one tile share the XCD L2).
#define SWZ(r) ((((r) + ((r) >> 3)) & 7) << 4)
__global__ __launch_bounds__(256, 2) void proj_kernel(
    const float* __restrict__ x, const u16* __restrict__ wcat,
    u16* __restrict__ q_t, u16* __restrict__ k_t, u16* __restrict__ gvt) {
  __shared__ __align__(16) char sm[34816];   // A dbuf 2x16K; epilogue ot aliases
  float* ot = (float*)sm;
  const int tid = threadIdx.x;
  const int w = tid >> 6, lane = tid & 63, lo = lane & 15, hi = lane >> 4;
  const int bid = blockIdx.x;
  const int xcd = bid & 7, slot = bid >> 3;
  const int y = slot % 3, t8 = slot / 3;
  const int tile = t8 * 8 + xcd;
  const int b = tile >> 5, n0 = (tile & 31) * 128;

  const float* xb = x + (size_t)b * (C_ * N_) + n0;
  const u16* wy = wcat + y * 131072;
  const int cq = tid >> 4, nq = tid & 15;   // staging: lanes n-fastest (512B runs)

  f32x4 acc[2][8];
#pragma unroll
  for (int s = 0; s < 2; ++s)
#pragma unroll
    for (int ft = 0; ft < 8; ++ft)
#pragma unroll
      for (int j = 0; j < 4; ++j) acc[s][ft][j] = 0.f;

  float4 xa[8];
  s16x8 bA[8], bB[8];

#define LOADX(c0)                                                        \
  {                                                                      \
    _Pragma("unroll") for (int i = 0; i < 4; ++i) {                      \
      const float* p = xb + (size_t)((c0) + cq * 4 + i) * N_ + nq * 8;   \
      xa[i * 2] = *(const float4*)p;                                     \
      xa[i * 2 + 1] = *(const float4*)(p + 4);                           \
    }                                                                    \
  }
#define STOREA(bufsel)                                                   \
  {                                                                      \
    char* ab = sm + (bufsel)*16384;                                      \
    _Pragma("unroll") for (int j = 0; j < 8; ++j) {                      \
      float v0 = xa[0 + (j >> 2)][j & 3];                                \
      float v1 = xa[2 + (j >> 2)][j & 3];                                \
      float v2 = xa[4 + (j >> 2)][j & 3];                                \
      float v3 = xa[6 + (j >> 2)][j & 3];                                \
      uint2 pk;                                                          \
      pk.x = pkbf(v0, v1);                                               \
      pk.y = pkbf(v2, v3);                                               \
      int r = nq * 8 + j;                                                \
      *(uint2*)(ab + r * 128 + ((cq * 8) ^ SWZ(r))) = pk;                \
    }                                                                    \
  }
#define LOADB(dst, kk2, ks)                                              \
  {                                                                      \
    _Pragma("unroll") for (int ft = 0; ft < 8; ++ft) dst[ft] =           \
        *(const s16x8*)(wy + (((kk2)*2 + (ks)) * 8 + ft) * 512 +         \
                        lo * 32 + hi * 8);                               \
  }
#define COMPUTE(bufsel, ks, bf)                                          \
  {                                                                      \
    const char* ab = sm + (bufsel)*16384;                                \
    _Pragma("unroll") for (int s = 0; s < 2; ++s) {                      \
      int r = w * 32 + s * 16 + lo;                                      \
      s16x8 af = *(const s16x8*)(ab + r * 128 +                          \
                                 (((ks)*64 + hi * 16) ^ SWZ(r)));        \
      _Pragma("unroll") for (int ft = 0; ft < 8; ++ft) acc[s][ft] =      \
          __builtin_amdgcn_mfma_f32_16x16x32_bf16(af, bf[ft],            \
                                                  acc[s][ft], 0, 0, 0);  \
    }                                                                    \
  }

  LOADX(0);
  LOADB(bA, 0, 0);
  STOREA(0);
  __syncthreads();

  for (int k = 0; k < 16; ++k) {
    if (k < 15) LOADX((k + 1) * 64);
    LOADB(bB, k, 1);
    COMPUTE(k & 1, 0, bA);
    if (k < 15) LOADB(bA, k + 1, 0);
    COMPUTE(k & 1, 1, bB);
    if (k < 15) STOREA((k & 1) ^ 1);
    __syncthreads();
  }

  // epilogue: two 64-row halves through f32 LDS transpose
  const float sc = (y == 0) ? LOG2E : 1.f;
#pragma unroll
  for (int hn = 0; hn < 2; ++hn) {
    if ((w >> 1) == hn) {
#pragma unroll
      for (int s = 0; s < 2; ++s)
#pragma unroll
        for (int ft = 0; ft < 8; ++ft)
#pragma unroll
          for (int j = 0; j < 4; ++j)
            ot[((w & 1) * 32 + s * 16 + hi * 4 + j) * 136 + ft * 16 + lo] =
                acc[s][ft][j] * sc;
    }
    __syncthreads();
    if (y < 2) {
      u16* arr = (y == 0) ? q_t : k_t;
      const int row = tid >> 2, fc = (tid & 3) * 32;
      u16* dst = arr + (size_t)(b * N_ + n0 + hn * 64 + row) * FD_ + fc;
      const float* sp = ot + row * 136 + fc;
#pragma unroll
      for (int k2 = 0; k2 < 4; ++k2) {
        s16x8 vv;
#pragma unroll
        for (int i = 0; i < 8; ++i) vv[i] = (short)f2bf(sp[k2 * 8 + i]);
        *(s16x8*)(dst + k2 * 8) = vv;
      }
    } else {
      // gvt[b][128 t2][4 ch][128 f][8k], tau32 within each 32-key tile
      const int f = tid >> 1, sel = tid & 1;
      const int t2 = (n0 >> 5) + hn * 2 + sel;
      u16* dstb = gvt + ((size_t)(b * 128 + t2) * 4) * 1024;
#pragma unroll
      for (int ch = 0; ch < 4; ++ch) {
        s16x8 vv;
#pragma unroll
        for (int kk = 0; kk < 8; ++kk) {
          int row = sel * 32 + tau32(ch * 8 + kk);
          vv[kk] = (short)f2bf(ot[row * 136 + f]);
        }
        *(s16x8*)(dstb + (ch * 128 + f) * 8) = vv;
      }
    }
    __syncthreads();
  }
#undef LOADX
#undef STOREA
#undef LOADB
#undef COMPUTE
}

// ============================ fused attention, N-way uniform KV-split ======
// 4 waves x 32 q = 128 q/block, staged dbuf KVBLK=32 (R10 structure).
// NSEG==5: {pool[0,32), pool[32,64), SA 43/43/42}, grid 1280 = 5 blocks/CU;
// every segment emits normalized partial + LSE (uniform, no mid-finalize).
// NSEG==3: {pool64, SA64, SA64}, grid 768 (R10-exact). NSEG==1: monolithic.
__global__ __launch_bounds__(256, 5) void attn_kernel(
    const u16* __restrict__ q_t, const u16* __restrict__ k_t,
    const u16* __restrict__ pool_k, const u16* __restrict__ pool_vt,
    const u16* __restrict__ gvt, u16* __restrict__ feat1,
    u16* __restrict__ parts, float* __restrict__ lse, const int NSEG) {
  __shared__ __align__(16) char smem[32768];   // K dbuf 16K | V dbuf 16K
  char* kB = smem;
  char* vB = smem + 16384;

  const int tid = threadIdx.x;
  const int w = tid >> 6, lane = tid & 63, lo = lane & 15, hi = lane >> 4;
  const int b = blockIdx.x & 7;
  const int nt = (blockIdx.x >> 3) & 31;
  const int sid = (int)(blockIdx.x >> 8);
  const int n0 = nt * 128;
  const bool DOPOOL = (NSEG == 1);

  const int k_dr = lane >> 4, k_cb = (lane & 15) * 16;
  const int sw = (lo & 7) << 4;

  const char* ktb = (const char*)(k_t + (size_t)b * N_ * FD_);
  const char* vtb = (const char*)(gvt + (size_t)b * 128 * 4096);
  const char* kseg0;
  const char* vseg0;
  const char* kseg1;
  const char* vseg1;
  int tcnt;
  if (NSEG == 5) {
    switch (sid) {
      case 0:  kseg0 = (const char*)pool_k; vseg0 = (const char*)pool_vt; tcnt = 32; break;
      case 1:  kseg0 = (const char*)pool_k + 262144; vseg0 = (const char*)pool_vt + 262144; tcnt = 32; break;
      case 2:  kseg0 = ktb;            vseg0 = vtb;            tcnt = 43; break;
      case 3:  kseg0 = ktb + 352256;   vseg0 = vtb + 352256;   tcnt = 43; break;
      default: kseg0 = ktb + 704512;   vseg0 = vtb + 704512;   tcnt = 42; break;
    }
    kseg1 = kseg0 + 524288; vseg1 = vseg0 + 524288;  // unused (tcnt<=64)
  } else if (NSEG == 3) {
    if (sid == 0) { kseg0 = (const char*)pool_k; vseg0 = (const char*)pool_vt; }
    else { kseg0 = ktb + (size_t)(sid - 1) * 524288; vseg0 = vtb + (size_t)(sid - 1) * 524288; }
    kseg1 = kseg0 + 524288; vseg1 = vseg0 + 524288;  // unused
    tcnt = 64;
  } else {
    kseg0 = (const char*)pool_k; vseg0 = (const char*)pool_vt;
    kseg1 = ktb; vseg1 = vtb;
    tcnt = 192;
  }

  // Q fragments (theta, pre-scaled by LOG2E): wave w owns q rows n0+w*32..+31
  s16x8 q[2][4];
#pragma unroll
  for (int qf = 0; qf < 2; ++qf) {
    const u16* qbase = q_t + (size_t)(b * N_ + n0 + w * 32 + qf * 16 + lo) * FD_;
#pragma unroll
    for (int kk = 0; kk < 4; ++kk) q[qf][kk] = *(const s16x8*)(qbase + kk * 32 + hi * 8);
  }

  float m_r = -__builtin_inff();
  float l_r[2] = {0.f, 0.f};
  f32x4 o[2][8];
  u32 o1p[2][8][2];
#pragma unroll
  for (int qf = 0; qf < 2; ++qf)
#pragma unroll
    for (int ft = 0; ft < 8; ++ft) {
#pragma unroll
      for (int j = 0; j < 4; ++j) o[qf][ft][j] = 0.f;
      o1p[qf][ft][0] = 0u;
      o1p[qf][ft][1] = 0u;
    }

#define STAGE(i, bufsel)                                                   \
  {                                                                        \
    const char* kg = ((i) < 64) ? kseg0 + (size_t)(i)*8192                 \
                                : kseg1 + (size_t)((i)-64) * 8192;         \
    const char* vg = ((i) < 64) ? vseg0 + (size_t)(i)*8192                 \
                                : vseg1 + (size_t)((i)-64) * 8192;         \
    char* kl = kB + (bufsel)*8192;                                         \
    char* vl = vB + (bufsel)*8192;                                         \
    _Pragma("unroll") for (int cc2 = 0; cc2 < 2; ++cc2) {                  \
      int c = w * 2 + cc2;                                                 \
      int rl = c * 4 + k_dr;                                               \
      gl16(kg + rl * 256 + (k_cb ^ ((rl & 7) << 4)), kl + c * 1024);       \
      gl16(vg + c * 1024 + lane * 16, vl + c * 1024);                      \
    }                                                                      \
  }

  STAGE(0, 0);
  __syncthreads();

  int buf = 0;
  for (int i = 0; i < tcnt; ++i) {
    if (i + 1 < tcnt) STAGE(i + 1, buf ^ 1);
    if (DOPOOL && i == 64) {   // NSEG==1: finalize pool phase
#pragma unroll
      for (int qf = 0; qf < 2; ++qf) {
        float lq = l_r[qf];
        lq += __shfl_xor(lq, 16);
        lq += __shfl_xor(lq, 32);
        float inv = __builtin_amdgcn_rcpf(lq);
#pragma unroll
        for (int ft = 0; ft < 8; ++ft) {
          o1p[qf][ft][0] = pkbf(o[qf][ft][0] * inv, o[qf][ft][1] * inv);
          o1p[qf][ft][1] = pkbf(o[qf][ft][2] * inv, o[qf][ft][3] * inv);
#pragma unroll
          for (int j = 0; j < 4; ++j) o[qf][ft][j] = 0.f;
        }
        l_r[qf] = 0.f;
      }
      m_r = -__builtin_inff();
    }

    const char* kbc = kB + buf * 8192;
    const char* vbc = vB + buf * 8192;

    // S^T = mfma(K, Q)
    f32x4 s[2][2];
#pragma unroll
    for (int qf = 0; qf < 2; ++qf)
#pragma unroll
      for (int t = 0; t < 2; ++t)
#pragma unroll
        for (int j = 0; j < 4; ++j) s[qf][t][j] = 0.f;
    __builtin_amdgcn_s_setprio(1);
#pragma unroll
    for (int kk = 0; kk < 4; ++kk) {
      const int cb = (kk * 64 + hi * 16) ^ sw;
      s16x8 kf0 = *(const s16x8*)(kbc + lo * 256 + cb);
      s16x8 kf1 = *(const s16x8*)(kbc + (16 + lo) * 256 + cb);
#pragma unroll
      for (int qf = 0; qf < 2; ++qf) {
        s[qf][0] = __builtin_amdgcn_mfma_f32_16x16x32_bf16(kf0, q[qf][kk], s[qf][0], 0, 0, 0);
        s[qf][1] = __builtin_amdgcn_mfma_f32_16x16x32_bf16(kf1, q[qf][kk], s[qf][1], 0, 0, 0);
      }
    }
    __builtin_amdgcn_s_setprio(0);
    // lane-max check; wave max + rescale only in the rare branch (defer-max)
    float lm = fmaxf(
        fmaxf(fmaxf(fmaxf(s[0][0][0], s[0][0][1]), fmaxf(s[0][0][2], s[0][0][3])),
              fmaxf(fmaxf(s[0][1][0], s[0][1][1]), fmaxf(s[0][1][2], s[0][1][3]))),
        fmaxf(fmaxf(fmaxf(s[1][0][0], s[1][0][1]), fmaxf(s[1][0][2], s[1][0][3])),
              fmaxf(fmaxf(s[1][1][0], s[1][1][1]), fmaxf(s[1][1][2], s[1][1][3]))));
    if (__any(lm - m_r > 11.5f)) {
      float tm = fmaxf(lm, __shfl_xor(lm, 16));
      tm = fmaxf(tm, __shfl_xor(tm, 32));
      float mn = fmaxf(m_r, tm);
      float al = exp2f(m_r - mn);
      m_r = mn;
      l_r[0] *= al;
      l_r[1] *= al;
#pragma unroll
      for (int qf = 0; qf < 2; ++qf)
#pragma unroll
        for (int ft = 0; ft < 8; ++ft)
#pragma unroll
          for (int j = 0; j < 4; ++j) o[qf][ft][j] *= al;
    }
    // P = exp2(S - m); partial row sums; pack directly to PV B-frags
    union Frag { u32 u[4]; s16x8 v; };
    Frag pb[2];
#pragma unroll
    for (int qf = 0; qf < 2; ++qf) {
      float rs = 0.f;
#pragma unroll
      for (int t = 0; t < 2; ++t)
#pragma unroll
        for (int j = 0; j < 4; ++j) {
          float p = exp2f(s[qf][t][j] - m_r);
          s[qf][t][j] = p;
          rs += p;
        }
      l_r[qf] += rs;
      pb[qf].u[0] = pkbf(s[qf][0][0], s[qf][0][1]);
      pb[qf].u[1] = pkbf(s[qf][0][2], s[qf][0][3]);
      pb[qf].u[2] = pkbf(s[qf][1][0], s[qf][1][1]);
      pb[qf].u[3] = pkbf(s[qf][1][2], s[qf][1][3]);
    }
    // PV
    __builtin_amdgcn_s_setprio(1);
#pragma unroll
    for (int ft = 0; ft < 8; ++ft) {
      const int f = ft * 16 + lo;
      s16x8 vf = *(const s16x8*)(vbc + hi * 2048 + f * 16);
      o[0][ft] = __builtin_amdgcn_mfma_f32_16x16x32_bf16(vf, pb[0].v, o[0][ft], 0, 0, 0);
      o[1][ft] = __builtin_amdgcn_mfma_f32_16x16x32_bf16(vf, pb[1].v, o[1][ft], 0, 0, 0);
    }
    __builtin_amdgcn_s_setprio(0);
    __syncthreads();   // drains prefetch + protects buf swap
    buf ^= 1;
  }
#undef STAGE

  // epilogue
#pragma unroll
  for (int qf = 0; qf < 2; ++qf) {
    float lq = l_r[qf];
    lq += __shfl_xor(lq, 16);
    lq += __shfl_xor(lq, 32);
    float inv = __builtin_amdgcn_rcpf(lq);
    const size_t row = (size_t)(b * N_ + n0 + w * 32 + qf * 16 + lo);
    if (NSEG == 1) {
#pragma unroll
      for (int ft = 0; ft < 8; ++ft) {
        float v0 = lo16(o1p[qf][ft][0]) + o[qf][ft][0] * inv;
        float v1 = hi16(o1p[qf][ft][0]) + o[qf][ft][1] * inv;
        float v2 = lo16(o1p[qf][ft][1]) + o[qf][ft][2] * inv;
        float v3 = hi16(o1p[qf][ft][1]) + o[qf][ft][3] * inv;
        uint2 st = {pkbf(v0, v1), pkbf(v2, v3)};
        *(uint2*)(feat1 + row * FD_ + ft * 16 + hi * 4) = st;
      }
    } else {
      u16* dst = parts + (size_t)sid * 4194304;
#pragma unroll
      for (int ft = 0; ft < 8; ++ft) {
        uint2 st = {pkbf(o[qf][ft][0] * inv, o[qf][ft][1] * inv),
                    pkbf(o[qf][ft][2] * inv, o[qf][ft][3] * inv)};
        *(uint2*)(dst + row * FD_ + ft * 16 + hi * 4) = st;
      }
      if ((NSEG == 5 || sid > 0) && hi == 0) {
        int lslot = (NSEG == 5) ? sid : sid - 1;
        lse[lslot * 32768 + row] = m_r + log2f(lq);
      }
    }
  }
}

// ============================ merge3: featq = parts0 + combine(parts1,2) ====
__global__ __launch_bounds__(256) void merge3_kernel(
    const u16* __restrict__ parts, const float* __restrict__ lse,
    u16* __restrict__ featq) {
  const int tid = threadIdx.x;
  const int n = blockIdx.x * 32 + (tid >> 3);
  const int fc = (tid & 7) * 16;
  float l1 = lse[n], l2 = lse[32768 + n];
  float mx = fmaxf(l1, l2);
  float w1 = exp2f(l1 - mx), w2 = exp2f(l2 - mx);
  float dn = __builtin_amdgcn_rcpf(w1 + w2);
  float a1 = w1 * dn, a2 = w2 * dn;
  const size_t base = (size_t)n * FD_ + fc;
#pragma unroll
  for (int h = 0; h < 2; ++h) {
    s16x8 xp = *(const s16x8*)(parts + base + h * 8);
    s16x8 x1 = *(const s16x8*)(parts + 4194304 + base + h * 8);
    s16x8 x2 = *(const s16x8*)(parts + 8388608 + base + h * 8);
    s16x8 r;
#pragma unroll
    for (int i = 0; i < 8; ++i) {
      float v = bf2f((u16)xp[i]) + bf2f((u16)x1[i]) * a1 + bf2f((u16)x2[i]) * a2;
      r[i] = (short)f2bf(v);
    }
    *(s16x8*)(featq + base + h * 8) = r;
  }
}

// ============================ merge5: pool pair + SA triple, lse-weighted ===
__global__ __launch_bounds__(256) void merge5_kernel(
    const u16* __restrict__ parts, const float* __restrict__ lse,
    u16* __restrict__ featq) {
  const int tid = threadIdx.x;
  const int n = blockIdx.x * 32 + (tid >> 3);
  const int fc = (tid & 7) * 16;
  float l0 = lse[n], l1 = lse[32768 + n];
  float l2 = lse[65536 + n], l3 = lse[98304 + n], l4 = lse[131072 + n];
  float mp = fmaxf(l0, l1);
  float w0 = exp2f(l0 - mp), w1 = exp2f(l1 - mp);
  float dp = __builtin_amdgcn_rcpf(w0 + w1);
  float a0 = w0 * dp, a1 = w1 * dp;
  float ms = fmaxf(fmaxf(l2, l3), l4);
  float w2 = exp2f(l2 - ms), w3 = exp2f(l3 - ms), w4 = exp2f(l4 - ms);
  float ds = __builtin_amdgcn_rcpf(w2 + w3 + w4);
  float a2 = w2 * ds, a3 = w3 * ds, a4 = w4 * ds;
  const size_t base = (size_t)n * FD_ + fc;
#pragma unroll
  for (int h = 0; h < 2; ++h) {
    s16x8 p0 = *(const s16x8*)(parts + base + h * 8);
    s16x8 p1 = *(const s16x8*)(parts + 4194304 + base + h * 8);
    s16x8 p2 = *(const s16x8*)(parts + 8388608 + base + h * 8);
    s16x8 p3 = *(const s16x8*)(parts + 12582912 + base + h * 8);
    s16x8 p4 = *(const s16x8*)(parts + 16777216 + base + h * 8);
    s16x8 r;
#pragma unroll
    for (int i = 0; i < 8; ++i) {
      float v = bf2f((u16)p0[i]) * a0 + bf2f((u16)p1[i]) * a1 +
                bf2f((u16)p2[i]) * a2 + bf2f((u16)p3[i]) * a3 +
                bf2f((u16)p4[i]) * a4;
      r[i] = (short)f2bf(v);
    }
    *(s16x8*)(featq + base + h * 8) = r;
  }
}

// ============================ final: out = gamma * (w_o @ feat) + x =========
__global__ __launch_bounds__(256) void final_kernel(
    const float* __restrict__ x, const u16* __restrict__ wo_bf,
    const u16* __restrict__ feat, const float* __restrict__ gamma,
    float* __restrict__ out) {
  __shared__ __align__(16) char sm[17408];   // stage 16K; epilogue fl aliases
  float* fl = (float*)sm;
  const int tid = threadIdx.x;
  const int w = tid >> 6, lane = tid & 63, lo = lane & 15, hi = lane >> 4;
  const int n0 = blockIdx.x * 64, c0 = blockIdx.y * 64, b = blockIdx.z;

  // stage feat tile [64 n][128 f] (16KB), source pre-swizzled
  {
    const char* fb = (const char*)(feat + (size_t)(b * N_ + n0) * FD_);
#pragma unroll
    for (int r2 = 0; r2 < 4; ++r2) {
      int off = r2 * 4096 + tid * 16;
      int row = off >> 8, colb = off & 255;
      gl16(fb + row * 256 + (colb ^ ((row & 7) << 4)), sm + off);
    }
  }
  // prefetch wo fragments
  const u16* arow = wo_bf + (c0 + w * 16 + lo) * FD_ + hi * 8;
  s16x8 af[4];
#pragma unroll
  for (int kk = 0; kk < 4; ++kk) af[kk] = *(const s16x8*)(arow + kk * 32);

  f32x4 acc[4];
#pragma unroll
  for (int i = 0; i < 4; ++i)
#pragma unroll
    for (int j = 0; j < 4; ++j) acc[i][j] = 0.f;

  __syncthreads();   // staging complete

  const int swf = (lo & 7) << 4;
#pragma unroll
  for (int kk = 0; kk < 4; ++kk)
#pragma unroll
    for (int nt = 0; nt < 4; ++nt) {
      const int row = nt * 16 + lo;
      s16x8 bf = *(const s16x8*)(sm + row * 256 + ((kk * 64 + hi * 16) ^ swf));
      acc[nt] = __builtin_amdgcn_mfma_f32_16x16x32_bf16(af[kk], bf, acc[nt], 0, 0, 0);
    }

  __syncthreads();   // LDS reads done before fl overwrite
#pragma unroll
  for (int nt = 0; nt < 4; ++nt)
#pragma unroll
    for (int j = 0; j < 4; ++j)
      fl[(w * 16 + hi * 4 + j) * 68 + nt * 16 + lo] = acc[nt][j];
  __syncthreads();
  const float gm = gamma[0];
  const int cl = tid >> 2, nc = (tid & 3) * 16;
  const size_t xo = (size_t)b * C_ * N_ + (size_t)(c0 + cl) * N_ + n0 + nc;
  const float* sp = fl + cl * 68 + nc;
#pragma unroll
  for (int k2 = 0; k2 < 4; ++k2) {
    float4 v = *(const float4*)(sp + k2 * 4);
    float4 xi = *(const float4*)(x + xo + k2 * 4);
    float4 r;
    r.x = gm * v.x + xi.x;
    r.y = gm * v.y + xi.y;
    r.z = gm * v.z + xi.z;
    r.w = gm * v.w + xi.w;
    *(float4*)(out + xo + k2 * 4) = r;
  }
}

// ============================ launch =======================================
extern "C" void kernel_launch(void* const* d_in, const int* in_sizes, int n_in,
                              void* d_out, int out_size, void* d_ws, size_t ws_size,
                              hipStream_t stream) {
  const float* x = (const float*)d_in[0];
  const float* wth = (const float*)d_in[1];
  const float* wph = (const float*)d_in[2];
  const float* wg = (const float*)d_in[3];
  const float* wo = (const float*)d_in[4];
  const float* gamma = (const float*)d_in[5];
  const float* pool = (const float*)d_in[6];
  float* out = (float*)d_out;

  char* ws = (char*)d_ws;
  u16* wcat    = (u16*)(ws + 0);          //  384*1024*2 = 786432
  u16* wo_bf   = (u16*)(ws + 786432);     // 1024*128*2  = 262144
  u16* pool_k  = (u16*)(ws + 1048576);    // 2048*128*2  = 524288
  u16* pool_vt = (u16*)(ws + 1572864);    //  64*4*128*8*2 = 524288
  u16* q_t     = (u16*)(ws + 2097152);    // 8*4096*128*2 = 8388608
  u16* k_t     = (u16*)(ws + 10485760);   // 8*4096*128*2 = 8388608
  u16* gvt     = (u16*)(ws + 18874368);   // 8*128*4*128*8*2 = 8388608
  u16* parts   = (u16*)(ws + 27262976);   // up to 5 slots x 8388608
  u16* feat1   = (u16*)(ws + 27262976);   // NSEG==1 feat dest (aliases slot0)
  u16* featq   = q_t;                     // merged feat (q_t dead after attn)

  const size_t NEED5 = 69861376ull;       // 5 slots + 5*32768*4 lse
  const size_t NEED3 = 52690944ull;       // 3 slots + 2*32768*4 lse
  const int NSEG = (ws_size >= NEED5) ? 5 : (ws_size >= NEED3) ? 3 : 1;
  float* lse = (NSEG == 5) ? (float*)(ws + 69206016) : (float*)(ws + 52428800);

  prep_kernel<<<4096, 256, 0, stream>>>(wth, wph, wg, wo, pool, wcat, wo_bf, pool_k, pool_vt);
  proj_kernel<<<768, 256, 0, stream>>>(x, wcat, q_t, k_t, gvt);
  attn_kernel<<<(NSEG == 5) ? 1280 : (NSEG == 3) ? 768 : 256, 256, 0, stream>>>(
      q_t, k_t, pool_k, pool_vt, gvt, feat1, parts, lse, NSEG);
  const u16* featp = feat1;
  if (NSEG == 5) {
    merge5_kernel<<<1024, 256, 0, stream>>>(parts, lse, featq);
    featp = featq;
  } else if (NSEG == 3) {
    merge3_kernel<<<1024, 256, 0, stream>>>(parts, lse, featq);
    featp = featq;
  }
  final_kernel<<<dim3(64, 16, 8), 256, 0, stream>>>(x, wo_bf, featp, gamma, out);
}

// Round 13
// 582.225 us; speedup vs baseline: 1.2401x; 1.2401x over previous
//
#include <hip/hip_runtime.h>

typedef unsigned short u16;
typedef unsigned int u32;
typedef float f32x4 __attribute__((ext_vector_type(4)));
typedef short s16x8 __attribute__((ext_vector_type(8)));

#define B_ 8
#define C_ 1024
#define N_ 4096
#define FD_ 128
#define P_ 2048
#define LOG2E 1.4426950408889634f

__device__ __forceinline__ u16 f2bf(float f) {
  u32 u = __float_as_uint(f);
  u32 r = (u + 0x7fffu + ((u >> 16) & 1u)) >> 16;
  return (u16)r;
}
__device__ __forceinline__ u32 pkbf(float a, float b) {  // {lo:bf16(a), hi:bf16(b)}
  u32 r;
  asm("v_cvt_pk_bf16_f32 %0, %1, %2" : "=v"(r) : "v"(a), "v"(b));
  return r;
}
__device__ __forceinline__ float lo16(u32 u) { return __uint_as_float(u << 16); }
__device__ __forceinline__ float hi16(u32 u) { return __uint_as_float(u & 0xffff0000u); }
__device__ __forceinline__ float bf2f(u16 u) { return __uint_as_float(((u32)u) << 16); }

#define AS1 __attribute__((address_space(1)))
#define AS3 __attribute__((address_space(3)))
__device__ __forceinline__ void gl16(const void* g, void* l) {
  __builtin_amdgcn_global_load_lds((AS1 const u32*)g, (AS3 u32*)l, 16, 0, 0);
}

// key permutation within a 32-key tile: V column c holds key tau32(c), so the
// S^T accumulator registers pack directly into the PV B-fragment (no shfl).
__device__ __forceinline__ int tau32(int c) {
  return ((c & 4) << 2) + ((c & 24) >> 1) + (c & 3);
}

// ============================ prep: fp32 -> bf16 weights / pool layouts =====
// wcatf fragment-linear layout so each proj LOADB reads one contiguous 1KB.
__global__ __launch_bounds__(256) void prep_kernel(
    const float* __restrict__ wth, const float* __restrict__ wph,
    const float* __restrict__ wg, const float* __restrict__ wo,
    const float* __restrict__ pool,
    u16* __restrict__ wcat, u16* __restrict__ wo_bf,
    u16* __restrict__ pool_k, u16* __restrict__ pool_vt) {
  int idx = blockIdx.x * 256 + threadIdx.x;
  if (idx < 393216) {                       // wcatf[3][16][2][8][16][4][8]
    int o = idx;
    int e = o & 7, hi2 = (o >> 3) & 3, lo2 = (o >> 5) & 15;
    int ft = (o >> 9) & 7, ks = (o >> 12) & 1, kk2 = (o >> 13) & 15;
    int y = o >> 17;
    int c = kk2 * 64 + ks * 32 + hi2 * 8 + e;
    int fj = y * 128 + ft * 16 + lo2;
    float v = (fj < 128) ? wth[fj * 1024 + c]
              : (fj < 256 ? wph[(fj - 128) * 1024 + c]
                          : wg[(fj - 256) * 1024 + c]);
    wcat[idx] = f2bf(v);
  } else if (idx < 524288) {                // wo_bf[1024][128]
    int i = idx - 393216;
    wo_bf[i] = f2bf(wo[i]);
  } else if (idx < 786432) {                // pool_k[2048][128] = pool^T
    int i = idx - 524288;
    int p = i >> 7, f = i & 127;
    pool_k[i] = f2bf(pool[f * 2048 + p]);
  } else if (idx < 1048576) {               // pool_vt[64 tiles][4 ch][128 f][8k]
    int j = idx - 786432;
    int tile = j >> 12, r = j & 4095;
    int ch = r >> 10, f = (r >> 3) & 127, kk = r & 7;
    pool_vt[j] = f2bf(pool[f * 2048 + tile * 32 + tau32(ch * 8 + kk)]);
  }
}

// ============================ proj: pipelined GEMM ==========================
// 768 blocks; XCD-partner decode (3 y-slices of one tile share the XCD L2).
#define SWZ(r) ((((r) + ((r) >> 3)) & 7) << 4)
__global__ __launch_bounds__(256, 2) void proj_kernel(
    const float* __restrict__ x, const u16* __restrict__ wcat,
    u16* __restrict__ q_t, u16* __restrict__ k_t, u16* __restrict__ gvt) {
  __shared__ __align__(16) char sm[34816];   // A dbuf 2x16K; epilogue ot aliases
  float* ot = (float*)sm;
  const int tid = threadIdx.x;
  const int w = tid >> 6, lane = tid & 63, lo = lane & 15, hi = lane >> 4;
  const int bid = blockIdx.x;
  const int xcd = bid & 7, slot = bid >> 3;
  const int y = slot % 3, t8 = slot / 3;
  const int tile = t8 * 8 + xcd;
  const int b = tile >> 5, n0 = (tile & 31) * 128;

  const float* xb = x + (size_t)b * (C_ * N_) + n0;
  const u16* wy = wcat + y * 131072;
  const int cq = tid >> 4, nq = tid & 15;   // staging: lanes n-fastest (512B runs)

  f32x4 acc[2][8];
#pragma unroll
  for (int s = 0; s < 2; ++s)
#pragma unroll
    for (int ft = 0; ft < 8; ++ft)
#pragma unroll
      for (int j = 0; j < 4; ++j) acc[s][ft][j] = 0.f;

  float4 xa[8];
  s16x8 bA[8], bB[8];

#define LOADX(c0)                                                        \
  {                                                                      \
    _Pragma("unroll") for (int i = 0; i < 4; ++i) {                      \
      const float* p = xb + (size_t)((c0) + cq * 4 + i) * N_ + nq * 8;   \
      xa[i * 2] = *(const float4*)p;                                     \
      xa[i * 2 + 1] = *(const float4*)(p + 4);                           \
    }                                                                    \
  }
#define STOREA(bufsel)                                                   \
  {                                                                      \
    char* ab = sm + (bufsel)*16384;                                      \
    _Pragma("unroll") for (int j = 0; j < 8; ++j) {                      \
      float v0 = xa[0 + (j >> 2)][j & 3];                                \
      float v1 = xa[2 + (j >> 2)][j & 3];                                \
      float v2 = xa[4 + (j >> 2)][j & 3];                                \
      float v3 = xa[6 + (j >> 2)][j & 3];                                \
      uint2 pk;                                                          \
      pk.x = pkbf(v0, v1);                                               \
      pk.y = pkbf(v2, v3);                                               \
      int r = nq * 8 + j;                                                \
      *(uint2*)(ab + r * 128 + ((cq * 8) ^ SWZ(r))) = pk;                \
    }                                                                    \
  }
#define LOADB(dst, kk2, ks)                                              \
  {                                                                      \
    _Pragma("unroll") for (int ft = 0; ft < 8; ++ft) dst[ft] =           \
        *(const s16x8*)(wy + (((kk2)*2 + (ks)) * 8 + ft) * 512 +         \
                        lo * 32 + hi * 8);                               \
  }
#define COMPUTE(bufsel, ks, bf)                                          \
  {                                                                      \
    const char* ab = sm + (bufsel)*16384;                                \
    _Pragma("unroll") for (int s = 0; s < 2; ++s) {                      \
      int r = w * 32 + s * 16 + lo;                                      \
      s16x8 af = *(const s16x8*)(ab + r * 128 +                          \
                                 (((ks)*64 + hi * 16) ^ SWZ(r)));        \
      _Pragma("unroll") for (int ft = 0; ft < 8; ++ft) acc[s][ft] =      \
          __builtin_amdgcn_mfma_f32_16x16x32_bf16(af, bf[ft],            \
                                                  acc[s][ft], 0, 0, 0);  \
    }                                                                    \
  }

  LOADX(0);
  LOADB(bA, 0, 0);
  STOREA(0);
  __syncthreads();

  for (int k = 0; k < 16; ++k) {
    if (k < 15) LOADX((k + 1) * 64);
    LOADB(bB, k, 1);
    COMPUTE(k & 1, 0, bA);
    if (k < 15) LOADB(bA, k + 1, 0);
    COMPUTE(k & 1, 1, bB);
    if (k < 15) STOREA((k & 1) ^ 1);
    __syncthreads();
  }

  // epilogue: two 64-row halves through f32 LDS transpose
  const float sc = (y == 0) ? LOG2E : 1.f;
#pragma unroll
  for (int hn = 0; hn < 2; ++hn) {
    if ((w >> 1) == hn) {
#pragma unroll
      for (int s = 0; s < 2; ++s)
#pragma unroll
        for (int ft = 0; ft < 8; ++ft)
#pragma unroll
          for (int j = 0; j < 4; ++j)
            ot[((w & 1) * 32 + s * 16 + hi * 4 + j) * 136 + ft * 16 + lo] =
                acc[s][ft][j] * sc;
    }
    __syncthreads();
    if (y < 2) {
      u16* arr = (y == 0) ? q_t : k_t;
      const int row = tid >> 2, fc = (tid & 3) * 32;
      u16* dst = arr + (size_t)(b * N_ + n0 + hn * 64 + row) * FD_ + fc;
      const float* sp = ot + row * 136 + fc;
#pragma unroll
      for (int k2 = 0; k2 < 4; ++k2) {
        s16x8 vv;
#pragma unroll
        for (int i = 0; i < 8; ++i) vv[i] = (short)f2bf(sp[k2 * 8 + i]);
        *(s16x8*)(dst + k2 * 8) = vv;
      }
    } else {
      // gvt[b][128 t2][4 ch][128 f][8k], tau32 within each 32-key tile
      const int f = tid >> 1, sel = tid & 1;
      const int t2 = (n0 >> 5) + hn * 2 + sel;
      u16* dstb = gvt + ((size_t)(b * 128 + t2) * 4) * 1024;
#pragma unroll
      for (int ch = 0; ch < 4; ++ch) {
        s16x8 vv;
#pragma unroll
        for (int kk = 0; kk < 8; ++kk) {
          int row = sel * 32 + tau32(ch * 8 + kk);
          vv[kk] = (short)f2bf(ot[row * 136 + f]);
        }
        *(s16x8*)(dstb + (ch * 128 + f) * 8) = vv;
      }
    }
    __syncthreads();
  }
#undef LOADX
#undef STOREA
#undef LOADB
#undef COMPUTE
}

// ============================ fused attention, N-way uniform KV-split ======
// 4 waves x 32 q = 128 q/block, staged dbuf KVBLK=32 (R10 structure).
// NSEG==5: {pool[0,32), pool[32,64), SA 43/43/42}, grid 1280; bounds (256,4)
// caps VGPR at 128 (no spill); at ~84 VGPR + 32KB LDS, HW co-schedules
// 5 blocks/CU anyway. NSEG==3: R10-exact. NSEG==1: monolithic fallback.
__global__ __launch_bounds__(256, 4) void attn_kernel(
    const u16* __restrict__ q_t, const u16* __restrict__ k_t,
    const u16* __restrict__ pool_k, const u16* __restrict__ pool_vt,
    const u16* __restrict__ gvt, u16* __restrict__ feat1,
    u16* __restrict__ parts, float* __restrict__ lse, const int NSEG) {
  __shared__ __align__(16) char smem[32768];   // K dbuf 16K | V dbuf 16K
  char* kB = smem;
  char* vB = smem + 16384;

  const int tid = threadIdx.x;
  const int w = tid >> 6, lane = tid & 63, lo = lane & 15, hi = lane >> 4;
  const int b = blockIdx.x & 7;
  const int nt = (blockIdx.x >> 3) & 31;
  const int sid = (int)(blockIdx.x >> 8);
  const int n0 = nt * 128;
  const bool DOPOOL = (NSEG == 1);

  const int k_dr = lane >> 4, k_cb = (lane & 15) * 16;
  const int sw = (lo & 7) << 4;

  const char* ktb = (const char*)(k_t + (size_t)b * N_ * FD_);
  const char* vtb = (const char*)(gvt + (size_t)b * 128 * 4096);
  const char* kseg0;
  const char* vseg0;
  const char* kseg1;
  const char* vseg1;
  int tcnt;
  if (NSEG == 5) {
    switch (sid) {
      case 0:  kseg0 = (const char*)pool_k; vseg0 = (const char*)pool_vt; tcnt = 32; break;
      case 1:  kseg0 = (const char*)pool_k + 262144; vseg0 = (const char*)pool_vt + 262144; tcnt = 32; break;
      case 2:  kseg0 = ktb;            vseg0 = vtb;            tcnt = 43; break;
      case 3:  kseg0 = ktb + 352256;   vseg0 = vtb + 352256;   tcnt = 43; break;
      default: kseg0 = ktb + 704512;   vseg0 = vtb + 704512;   tcnt = 42; break;
    }
    kseg1 = kseg0 + 524288; vseg1 = vseg0 + 524288;  // unused (tcnt<=64)
  } else if (NSEG == 3) {
    if (sid == 0) { kseg0 = (const char*)pool_k; vseg0 = (const char*)pool_vt; }
    else { kseg0 = ktb + (size_t)(sid - 1) * 524288; vseg0 = vtb + (size_t)(sid - 1) * 524288; }
    kseg1 = kseg0 + 524288; vseg1 = vseg0 + 524288;  // unused
    tcnt = 64;
  } else {
    kseg0 = (const char*)pool_k; vseg0 = (const char*)pool_vt;
    kseg1 = ktb; vseg1 = vtb;
    tcnt = 192;
  }

  // Q fragments (theta, pre-scaled by LOG2E): wave w owns q rows n0+w*32..+31
  s16x8 q[2][4];
#pragma unroll
  for (int qf = 0; qf < 2; ++qf) {
    const u16* qbase = q_t + (size_t)(b * N_ + n0 + w * 32 + qf * 16 + lo) * FD_;
#pragma unroll
    for (int kk = 0; kk < 4; ++kk) q[qf][kk] = *(const s16x8*)(qbase + kk * 32 + hi * 8);
  }

  float m_r = -__builtin_inff();
  float l_r[2] = {0.f, 0.f};
  f32x4 o[2][8];
  u32 o1p[2][8][2];
#pragma unroll
  for (int qf = 0; qf < 2; ++qf)
#pragma unroll
    for (int ft = 0; ft < 8; ++ft) {
#pragma unroll
      for (int j = 0; j < 4; ++j) o[qf][ft][j] = 0.f;
      o1p[qf][ft][0] = 0u;
      o1p[qf][ft][1] = 0u;
    }

#define STAGE(i, bufsel)                                                   \
  {                                                                        \
    const char* kg = ((i) < 64) ? kseg0 + (size_t)(i)*8192                 \
                                : kseg1 + (size_t)((i)-64) * 8192;         \
    const char* vg = ((i) < 64) ? vseg0 + (size_t)(i)*8192                 \
                                : vseg1 + (size_t)((i)-64) * 8192;         \
    char* kl = kB + (bufsel)*8192;                                         \
    char* vl = vB + (bufsel)*8192;                                         \
    _Pragma("unroll") for (int cc2 = 0; cc2 < 2; ++cc2) {                  \
      int c = w * 2 + cc2;                                                 \
      int rl = c * 4 + k_dr;                                               \
      gl16(kg + rl * 256 + (k_cb ^ ((rl & 7) << 4)), kl + c * 1024);       \
      gl16(vg + c * 1024 + lane * 16, vl + c * 1024);                      \
    }                                                                      \
  }

  STAGE(0, 0);
  __syncthreads();

  int buf = 0;
  for (int i = 0; i < tcnt; ++i) {
    if (i + 1 < tcnt) STAGE(i + 1, buf ^ 1);
    if (DOPOOL && i == 64) {   // NSEG==1: finalize pool phase
#pragma unroll
      for (int qf = 0; qf < 2; ++qf) {
        float lq = l_r[qf];
        lq += __shfl_xor(lq, 16);
        lq += __shfl_xor(lq, 32);
        float inv = __builtin_amdgcn_rcpf(lq);
#pragma unroll
        for (int ft = 0; ft < 8; ++ft) {
          o1p[qf][ft][0] = pkbf(o[qf][ft][0] * inv, o[qf][ft][1] * inv);
          o1p[qf][ft][1] = pkbf(o[qf][ft][2] * inv, o[qf][ft][3] * inv);
#pragma unroll
          for (int j = 0; j < 4; ++j) o[qf][ft][j] = 0.f;
        }
        l_r[qf] = 0.f;
      }
      m_r = -__builtin_inff();
    }

    const char* kbc = kB + buf * 8192;
    const char* vbc = vB + buf * 8192;

    // S^T = mfma(K, Q)
    f32x4 s[2][2];
#pragma unroll
    for (int qf = 0; qf < 2; ++qf)
#pragma unroll
      for (int t = 0; t < 2; ++t)
#pragma unroll
        for (int j = 0; j < 4; ++j) s[qf][t][j] = 0.f;
#pragma unroll
    for (int kk = 0; kk < 4; ++kk) {
      const int cb = (kk * 64 + hi * 16) ^ sw;
      s16x8 kf0 = *(const s16x8*)(kbc + lo * 256 + cb);
      s16x8 kf1 = *(const s16x8*)(kbc + (16 + lo) * 256 + cb);
#pragma unroll
      for (int qf = 0; qf < 2; ++qf) {
        s[qf][0] = __builtin_amdgcn_mfma_f32_16x16x32_bf16(kf0, q[qf][kk], s[qf][0], 0, 0, 0);
        s[qf][1] = __builtin_amdgcn_mfma_f32_16x16x32_bf16(kf1, q[qf][kk], s[qf][1], 0, 0, 0);
      }
    }
    // lane-max check; wave max + rescale only in the rare branch (defer-max)
    float lm = fmaxf(
        fmaxf(fmaxf(fmaxf(s[0][0][0], s[0][0][1]), fmaxf(s[0][0][2], s[0][0][3])),
              fmaxf(fmaxf(s[0][1][0], s[0][1][1]), fmaxf(s[0][1][2], s[0][1][3]))),
        fmaxf(fmaxf(fmaxf(s[1][0][0], s[1][0][1]), fmaxf(s[1][0][2], s[1][0][3])),
              fmaxf(fmaxf(s[1][1][0], s[1][1][1]), fmaxf(s[1][1][2], s[1][1][3]))));
    if (__any(lm - m_r > 11.5f)) {
      float tm = fmaxf(lm, __shfl_xor(lm, 16));
      tm = fmaxf(tm, __shfl_xor(tm, 32));
      float mn = fmaxf(m_r, tm);
      float al = exp2f(m_r - mn);
      m_r = mn;
      l_r[0] *= al;
      l_r[1] *= al;
#pragma unroll
      for (int qf = 0; qf < 2; ++qf)
#pragma unroll
        for (int ft = 0; ft < 8; ++ft)
#pragma unroll
          for (int j = 0; j < 4; ++j) o[qf][ft][j] *= al;
    }
    // P = exp2(S - m); partial row sums; pack directly to PV B-frags
    union Frag { u32 u[4]; s16x8 v; };
    Frag pb[2];
#pragma unroll
    for (int qf = 0; qf < 2; ++qf) {
      float rs = 0.f;
#pragma unroll
      for (int t = 0; t < 2; ++t)
#pragma unroll
        for (int j = 0; j < 4; ++j) {
          float p = exp2f(s[qf][t][j] - m_r);
          s[qf][t][j] = p;
          rs += p;
        }
      l_r[qf] += rs;
      pb[qf].u[0] = pkbf(s[qf][0][0], s[qf][0][1]);
      pb[qf].u[1] = pkbf(s[qf][0][2], s[qf][0][3]);
      pb[qf].u[2] = pkbf(s[qf][1][0], s[qf][1][1]);
      pb[qf].u[3] = pkbf(s[qf][1][2], s[qf][1][3]);
    }
    // PV
#pragma unroll
    for (int ft = 0; ft < 8; ++ft) {
      const int f = ft * 16 + lo;
      s16x8 vf = *(const s16x8*)(vbc + hi * 2048 + f * 16);
      o[0][ft] = __builtin_amdgcn_mfma_f32_16x16x32_bf16(vf, pb[0].v, o[0][ft], 0, 0, 0);
      o[1][ft] = __builtin_amdgcn_mfma_f32_16x16x32_bf16(vf, pb[1].v, o[1][ft], 0, 0, 0);
    }
    __syncthreads();   // drains prefetch + protects buf swap
    buf ^= 1;
  }
#undef STAGE

  // epilogue
#pragma unroll
  for (int qf = 0; qf < 2; ++qf) {
    float lq = l_r[qf];
    lq += __shfl_xor(lq, 16);
    lq += __shfl_xor(lq, 32);
    float inv = __builtin_amdgcn_rcpf(lq);
    const size_t row = (size_t)(b * N_ + n0 + w * 32 + qf * 16 + lo);
    if (NSEG == 1) {
#pragma unroll
      for (int ft = 0; ft < 8; ++ft) {
        float v0 = lo16(o1p[qf][ft][0]) + o[qf][ft][0] * inv;
        float v1 = hi16(o1p[qf][ft][0]) + o[qf][ft][1] * inv;
        float v2 = lo16(o1p[qf][ft][1]) + o[qf][ft][2] * inv;
        float v3 = hi16(o1p[qf][ft][1]) + o[qf][ft][3] * inv;
        uint2 st = {pkbf(v0, v1), pkbf(v2, v3)};
        *(uint2*)(feat1 + row * FD_ + ft * 16 + hi * 4) = st;
      }
    } else {
      u16* dst = parts + (size_t)sid * 4194304;
#pragma unroll
      for (int ft = 0; ft < 8; ++ft) {
        uint2 st = {pkbf(o[qf][ft][0] * inv, o[qf][ft][1] * inv),
                    pkbf(o[qf][ft][2] * inv, o[qf][ft][3] * inv)};
        *(uint2*)(dst + row * FD_ + ft * 16 + hi * 4) = st;
      }
      if ((NSEG == 5 || sid > 0) && hi == 0) {
        int lslot = (NSEG == 5) ? sid : sid - 1;
        lse[lslot * 32768 + row] = m_r + log2f(lq);
      }
    }
  }
}

// ============================ merge3: featq = parts0 + combine(parts1,2) ====
__global__ __launch_bounds__(256) void merge3_kernel(
    const u16* __restrict__ parts, const float* __restrict__ lse,
    u16* __restrict__ featq) {
  const int tid = threadIdx.x;
  const int n = blockIdx.x * 32 + (tid >> 3);
  const int fc = (tid & 7) * 16;
  float l1 = lse[n], l2 = lse[32768 + n];
  float mx = fmaxf(l1, l2);
  float w1 = exp2f(l1 - mx), w2 = exp2f(l2 - mx);
  float dn = __builtin_amdgcn_rcpf(w1 + w2);
  float a1 = w1 * dn, a2 = w2 * dn;
  const size_t base = (size_t)n * FD_ + fc;
#pragma unroll
  for (int h = 0; h < 2; ++h) {
    s16x8 xp = *(const s16x8*)(parts + base + h * 8);
    s16x8 x1 = *(const s16x8*)(parts + 4194304 + base + h * 8);
    s16x8 x2 = *(const s16x8*)(parts + 8388608 + base + h * 8);
    s16x8 r;
#pragma unroll
    for (int i = 0; i < 8; ++i) {
      float v = bf2f((u16)xp[i]) + bf2f((u16)x1[i]) * a1 + bf2f((u16)x2[i]) * a2;
      r[i] = (short)f2bf(v);
    }
    *(s16x8*)(featq + base + h * 8) = r;
  }
}

// ============================ merge5: pool pair + SA triple, lse-weighted ===
__global__ __launch_bounds__(256) void merge5_kernel(
    const u16* __restrict__ parts, const float* __restrict__ lse,
    u16* __restrict__ featq) {
  const int tid = threadIdx.x;
  const int n = blockIdx.x * 32 + (tid >> 3);
  const int fc = (tid & 7) * 16;
  float l0 = lse[n], l1 = lse[32768 + n];
  float l2 = lse[65536 + n], l3 = lse[98304 + n], l4 = lse[131072 + n];
  float mp = fmaxf(l0, l1);
  float w0 = exp2f(l0 - mp), w1 = exp2f(l1 - mp);
  float dp = __builtin_amdgcn_rcpf(w0 + w1);
  float a0 = w0 * dp, a1 = w1 * dp;
  float ms = fmaxf(fmaxf(l2, l3), l4);
  float w2 = exp2f(l2 - ms), w3 = exp2f(l3 - ms), w4 = exp2f(l4 - ms);
  float ds = __builtin_amdgcn_rcpf(w2 + w3 + w4);
  float a2 = w2 * ds, a3 = w3 * ds, a4 = w4 * ds;
  const size_t base = (size_t)n * FD_ + fc;
#pragma unroll
  for (int h = 0; h < 2; ++h) {
    s16x8 p0 = *(const s16x8*)(parts + base + h * 8);
    s16x8 p1 = *(const s16x8*)(parts + 4194304 + base + h * 8);
    s16x8 p2 = *(const s16x8*)(parts + 8388608 + base + h * 8);
    s16x8 p3 = *(const s16x8*)(parts + 12582912 + base + h * 8);
    s16x8 p4 = *(const s16x8*)(parts + 16777216 + base + h * 8);
    s16x8 r;
#pragma unroll
    for (int i = 0; i < 8; ++i) {
      float v = bf2f((u16)p0[i]) * a0 + bf2f((u16)p1[i]) * a1 +
                bf2f((u16)p2[i]) * a2 + bf2f((u16)p3[i]) * a3 +
                bf2f((u16)p4[i]) * a4;
      r[i] = (short)f2bf(v);
    }
    *(s16x8*)(featq + base + h * 8) = r;
  }
}

// ============================ final: out = gamma * (w_o @ feat) + x =========
__global__ __launch_bounds__(256) void final_kernel(
    const float* __restrict__ x, const u16* __restrict__ wo_bf,
    const u16* __restrict__ feat, const float* __restrict__ gamma,
    float* __restrict__ out) {
  __shared__ __align__(16) char sm[17408];   // stage 16K; epilogue fl aliases
  float* fl = (float*)sm;
  const int tid = threadIdx.x;
  const int w = tid >> 6, lane = tid & 63, lo = lane & 15, hi = lane >> 4;
  const int n0 = blockIdx.x * 64, c0 = blockIdx.y * 64, b = blockIdx.z;

  // stage feat tile [64 n][128 f] (16KB), source pre-swizzled
  {
    const char* fb = (const char*)(feat + (size_t)(b * N_ + n0) * FD_);
#pragma unroll
    for (int r2 = 0; r2 < 4; ++r2) {
      int off = r2 * 4096 + tid * 16;
      int row = off >> 8, colb = off & 255;
      gl16(fb + row * 256 + (colb ^ ((row & 7) << 4)), sm + off);
    }
  }
  // prefetch wo fragments
  const u16* arow = wo_bf + (c0 + w * 16 + lo) * FD_ + hi * 8;
  s16x8 af[4];
#pragma unroll
  for (int kk = 0; kk < 4; ++kk) af[kk] = *(const s16x8*)(arow + kk * 32);

  f32x4 acc[4];
#pragma unroll
  for (int i = 0; i < 4; ++i)
#pragma unroll
    for (int j = 0; j < 4; ++j) acc[i][j] = 0.f;

  __syncthreads();   // staging complete

  const int swf = (lo & 7) << 4;
#pragma unroll
  for (int kk = 0; kk < 4; ++kk)
#pragma unroll
    for (int nt = 0; nt < 4; ++nt) {
      const int row = nt * 16 + lo;
      s16x8 bf = *(const s16x8*)(sm + row * 256 + ((kk * 64 + hi * 16) ^ swf));
      acc[nt] = __builtin_amdgcn_mfma_f32_16x16x32_bf16(af[kk], bf, acc[nt], 0, 0, 0);
    }

  __syncthreads();   // LDS reads done before fl overwrite
#pragma unroll
  for (int nt = 0; nt < 4; ++nt)
#pragma unroll
    for (int j = 0; j < 4; ++j)
      fl[(w * 16 + hi * 4 + j) * 68 + nt * 16 + lo] = acc[nt][j];
  __syncthreads();
  const float gm = gamma[0];
  const int cl = tid >> 2, nc = (tid & 3) * 16;
  const size_t xo = (size_t)b * C_ * N_ + (size_t)(c0 + cl) * N_ + n0 + nc;
  const float* sp = fl + cl * 68 + nc;
#pragma unroll
  for (int k2 = 0; k2 < 4; ++k2) {
    float4 v = *(const float4*)(sp + k2 * 4);
    float4 xi = *(const float4*)(x + xo + k2 * 4);
    float4 r;
    r.x = gm * v.x + xi.x;
    r.y = gm * v.y + xi.y;
    r.z = gm * v.z + xi.z;
    r.w = gm * v.w + xi.w;
    *(float4*)(out + xo + k2 * 4) = r;
  }
}

// ============================ launch =======================================
extern "C" void kernel_launch(void* const* d_in, const int* in_sizes, int n_in,
                              void* d_out, int out_size, void* d_ws, size_t ws_size,
                              hipStream_t stream) {
  const float* x = (const float*)d_in[0];
  const float* wth = (const float*)d_in[1];
  const float* wph = (const float*)d_in[2];
  const float* wg = (const float*)d_in[3];
  const float* wo = (const float*)d_in[4];
  const float* gamma = (const float*)d_in[5];
  const float* pool = (const float*)d_in[6];
  float* out = (float*)d_out;

  char* ws = (char*)d_ws;
  u16* wcat    = (u16*)(ws + 0);          //  384*1024*2 = 786432
  u16* wo_bf   = (u16*)(ws + 786432);     // 1024*128*2  = 262144
  u16* pool_k  = (u16*)(ws + 1048576);    // 2048*128*2  = 524288
  u16* pool_vt = (u16*)(ws + 1572864);    //  64*4*128*8*2 = 524288
  u16* q_t     = (u16*)(ws + 2097152);    // 8*4096*128*2 = 8388608
  u16* k_t     = (u16*)(ws + 10485760);   // 8*4096*128*2 = 8388608
  u16* gvt     = (u16*)(ws + 18874368);   // 8*128*4*128*8*2 = 8388608
  u16* parts   = (u16*)(ws + 27262976);   // up to 5 slots x 8388608
  u16* feat1   = (u16*)(ws + 27262976);   // NSEG==1 feat dest (aliases slot0)
  u16* featq   = q_t;                     // merged feat (q_t dead after attn)

  const size_t NEED5 = 69861376ull;       // 5 slots + 5*32768*4 lse
  const size_t NEED3 = 52690944ull;       // 3 slots + 2*32768*4 lse
  const int NSEG = (ws_size >= NEED5) ? 5 : (ws_size >= NEED3) ? 3 : 1;
  float* lse = (NSEG == 5) ? (float*)(ws + 69206016) : (float*)(ws + 52428800);

  prep_kernel<<<4096, 256, 0, stream>>>(wth, wph, wg, wo, pool, wcat, wo_bf, pool_k, pool_vt);
  proj_kernel<<<768, 256, 0, stream>>>(x, wcat, q_t, k_t, gvt);
  attn_kernel<<<(NSEG == 5) ? 1280 : (NSEG == 3) ? 768 : 256, 256, 0, stream>>>(
      q_t, k_t, pool_k, pool_vt, gvt, feat1, parts, lse, NSEG);
  const u16* featp = feat1;
  if (NSEG == 5) {
    merge5_kernel<<<1024, 256, 0, stream>>>(parts, lse, featq);
    featp = featq;
  } else if (NSEG == 3) {
    merge3_kernel<<<1024, 256, 0, stream>>>(parts, lse, featq);
    featp = featq;
  }
  final_kernel<<<dim3(64, 16, 8), 256, 0, stream>>>(x, wo_bf, featp, gamma, out);
}

// Round 14
// 259.260 us; speedup vs baseline: 2.7849x; 2.2457x over previous
//
#include <hip/hip_runtime.h>

typedef unsigned short u16;
typedef unsigned int u32;
typedef float f32x4 __attribute__((ext_vector_type(4)));
typedef short s16x8 __attribute__((ext_vector_type(8)));

#define B_ 8
#define C_ 1024
#define N_ 4096
#define FD_ 128
#define P_ 2048
#define LOG2E 1.4426950408889634f

__device__ __forceinline__ u16 f2bf(float f) {
  u32 u = __float_as_uint(f);
  u32 r = (u + 0x7fffu + ((u >> 16) & 1u)) >> 16;
  return (u16)r;
}
__device__ __forceinline__ u32 pkbf(float a, float b) {  // {lo:bf16(a), hi:bf16(b)}
  u32 r;
  asm("v_cvt_pk_bf16_f32 %0, %1, %2" : "=v"(r) : "v"(a), "v"(b));
  return r;
}
__device__ __forceinline__ float lo16(u32 u) { return __uint_as_float(u << 16); }
__device__ __forceinline__ float hi16(u32 u) { return __uint_as_float(u & 0xffff0000u); }
__device__ __forceinline__ float bf2f(u16 u) { return __uint_as_float(((u32)u) << 16); }

#define AS1 __attribute__((address_space(1)))
#define AS3 __attribute__((address_space(3)))
__device__ __forceinline__ void gl16(const void* g, void* l) {
  __builtin_amdgcn_global_load_lds((AS1 const u32*)g, (AS3 u32*)l, 16, 0, 0);
}

// key permutation within a 32-key tile: V column c holds key tau32(c), so the
// S^T accumulator registers pack directly into the PV B-fragment (no shfl).
__device__ __forceinline__ int tau32(int c) {
  return ((c & 4) << 2) + ((c & 24) >> 1) + (c & 3);
}

// ============================ prep: fp32 -> bf16 weights / pool layouts =====
// wcatf fragment-linear layout so each proj LOADB reads one contiguous 1KB.
__global__ __launch_bounds__(256) void prep_kernel(
    const float* __restrict__ wth, const float* __restrict__ wph,
    const float* __restrict__ wg, const float* __restrict__ wo,
    const float* __restrict__ pool,
    u16* __restrict__ wcat, u16* __restrict__ wo_bf,
    u16* __restrict__ pool_k, u16* __restrict__ pool_vt) {
  int idx = blockIdx.x * 256 + threadIdx.x;
  if (idx < 393216) {                       // wcatf[3][16][2][8][16][4][8]
    int o = idx;
    int e = o & 7, hi2 = (o >> 3) & 3, lo2 = (o >> 5) & 15;
    int ft = (o >> 9) & 7, ks = (o >> 12) & 1, kk2 = (o >> 13) & 15;
    int y = o >> 17;
    int c = kk2 * 64 + ks * 32 + hi2 * 8 + e;
    int fj = y * 128 + ft * 16 + lo2;
    float v = (fj < 128) ? wth[fj * 1024 + c]
              : (fj < 256 ? wph[(fj - 128) * 1024 + c]
                          : wg[(fj - 256) * 1024 + c]);
    wcat[idx] = f2bf(v);
  } else if (idx < 524288) {                // wo_bf[1024][128]
    int i = idx - 393216;
    wo_bf[i] = f2bf(wo[i]);
  } else if (idx < 786432) {                // pool_k[2048][128] = pool^T
    int i = idx - 524288;
    int p = i >> 7, f = i & 127;
    pool_k[i] = f2bf(pool[f * 2048 + p]);
  } else if (idx < 1048576) {               // pool_vt[64 tiles][4 ch][128 f][8k]
    int j = idx - 786432;
    int tile = j >> 12, r = j & 4095;
    int ch = r >> 10, f = (r >> 3) & 127, kk = r & 7;
    pool_vt[j] = f2bf(pool[f * 2048 + tile * 32 + tau32(ch * 8 + kk)]);
  }
}

// ============================ proj: pipelined GEMM ==========================
// 768 blocks; XCD-partner decode (3 y-slices of one tile share the XCD L2).
#define SWZ(r) ((((r) + ((r) >> 3)) & 7) << 4)
__global__ __launch_bounds__(256, 2) void proj_kernel(
    const float* __restrict__ x, const u16* __restrict__ wcat,
    u16* __restrict__ q_t, u16* __restrict__ k_t, u16* __restrict__ gvt) {
  __shared__ __align__(16) char sm[34816];   // A dbuf 2x16K; epilogue ot aliases
  float* ot = (float*)sm;
  const int tid = threadIdx.x;
  const int w = tid >> 6, lane = tid & 63, lo = lane & 15, hi = lane >> 4;
  const int bid = blockIdx.x;
  const int xcd = bid & 7, slot = bid >> 3;
  const int y = slot % 3, t8 = slot / 3;
  const int tile = t8 * 8 + xcd;
  const int b = tile >> 5, n0 = (tile & 31) * 128;

  const float* xb = x + (size_t)b * (C_ * N_) + n0;
  const u16* wy = wcat + y * 131072;
  const int cq = tid >> 4, nq = tid & 15;   // staging: lanes n-fastest (512B runs)

  f32x4 acc[2][8];
#pragma unroll
  for (int s = 0; s < 2; ++s)
#pragma unroll
    for (int ft = 0; ft < 8; ++ft)
#pragma unroll
      for (int j = 0; j < 4; ++j) acc[s][ft][j] = 0.f;

  float4 xa[8];
  s16x8 bA[8], bB[8];

#define LOADX(c0)                                                        \
  {                                                                      \
    _Pragma("unroll") for (int i = 0; i < 4; ++i) {                      \
      const float* p = xb + (size_t)((c0) + cq * 4 + i) * N_ + nq * 8;   \
      xa[i * 2] = *(const float4*)p;                                     \
      xa[i * 2 + 1] = *(const float4*)(p + 4);                           \
    }                                                                    \
  }
#define STOREA(bufsel)                                                   \
  {                                                                      \
    char* ab = sm + (bufsel)*16384;                                      \
    _Pragma("unroll") for (int j = 0; j < 8; ++j) {                      \
      float v0 = xa[0 + (j >> 2)][j & 3];                                \
      float v1 = xa[2 + (j >> 2)][j & 3];                                \
      float v2 = xa[4 + (j >> 2)][j & 3];                                \
      float v3 = xa[6 + (j >> 2)][j & 3];                                \
      uint2 pk;                                                          \
      pk.x = pkbf(v0, v1);                                               \
      pk.y = pkbf(v2, v3);                                               \
      int r = nq * 8 + j;                                                \
      *(uint2*)(ab + r * 128 + ((cq * 8) ^ SWZ(r))) = pk;                \
    }                                                                    \
  }
#define LOADB(dst, kk2, ks)                                              \
  {                                                                      \
    _Pragma("unroll") for (int ft = 0; ft < 8; ++ft) dst[ft] =           \
        *(const s16x8*)(wy + (((kk2)*2 + (ks)) * 8 + ft) * 512 +         \
                        lo * 32 + hi * 8);                               \
  }
#define COMPUTE(bufsel, ks, bf)                                          \
  {                                                                      \
    const char* ab = sm + (bufsel)*16384;                                \
    _Pragma("unroll") for (int s = 0; s < 2; ++s) {                      \
      int r = w * 32 + s * 16 + lo;                                      \
      s16x8 af = *(const s16x8*)(ab + r * 128 +                          \
                                 (((ks)*64 + hi * 16) ^ SWZ(r)));        \
      _Pragma("unroll") for (int ft = 0; ft < 8; ++ft) acc[s][ft] =      \
          __builtin_amdgcn_mfma_f32_16x16x32_bf16(af, bf[ft],            \
                                                  acc[s][ft], 0, 0, 0);  \
    }                                                                    \
  }

  LOADX(0);
  LOADB(bA, 0, 0);
  STOREA(0);
  __syncthreads();

  for (int k = 0; k < 16; ++k) {
    if (k < 15) LOADX((k + 1) * 64);
    LOADB(bB, k, 1);
    COMPUTE(k & 1, 0, bA);
    if (k < 15) LOADB(bA, k + 1, 0);
    COMPUTE(k & 1, 1, bB);
    if (k < 15) STOREA((k & 1) ^ 1);
    __syncthreads();
  }

  // epilogue: two 64-row halves through f32 LDS transpose
  const float sc = (y == 0) ? LOG2E : 1.f;
#pragma unroll
  for (int hn = 0; hn < 2; ++hn) {
    if ((w >> 1) == hn) {
#pragma unroll
      for (int s = 0; s < 2; ++s)
#pragma unroll
        for (int ft = 0; ft < 8; ++ft)
#pragma unroll
          for (int j = 0; j < 4; ++j)
            ot[((w & 1) * 32 + s * 16 + hi * 4 + j) * 136 + ft * 16 + lo] =
                acc[s][ft][j] * sc;
    }
    __syncthreads();
    if (y < 2) {
      u16* arr = (y == 0) ? q_t : k_t;
      const int row = tid >> 2, fc = (tid & 3) * 32;
      u16* dst = arr + (size_t)(b * N_ + n0 + hn * 64 + row) * FD_ + fc;
      const float* sp = ot + row * 136 + fc;
#pragma unroll
      for (int k2 = 0; k2 < 4; ++k2) {
        s16x8 vv;
#pragma unroll
        for (int i = 0; i < 8; ++i) vv[i] = (short)f2bf(sp[k2 * 8 + i]);
        *(s16x8*)(dst + k2 * 8) = vv;
      }
    } else {
      // gvt[b][128 t2][4 ch][128 f][8k], tau32 within each 32-key tile
      const int f = tid >> 1, sel = tid & 1;
      const int t2 = (n0 >> 5) + hn * 2 + sel;
      u16* dstb = gvt + ((size_t)(b * 128 + t2) * 4) * 1024;
#pragma unroll
      for (int ch = 0; ch < 4; ++ch) {
        s16x8 vv;
#pragma unroll
        for (int kk = 0; kk < 8; ++kk) {
          int row = sel * 32 + tau32(ch * 8 + kk);
          vv[kk] = (short)f2bf(ot[row * 136 + f]);
        }
        *(s16x8*)(dstb + (ch * 128 + f) * 8) = vv;
      }
    }
    __syncthreads();
  }
#undef LOADX
#undef STOREA
#undef LOADB
#undef COMPUTE
}

// ============================ fused attention, 3-way KV-split ==============
// 4 waves x 32 q = 128 q/block, staged dbuf KVBLK=32 (R10-exact structure,
// launch_bounds(256,3): ~84 VGPR + 64 AGPR fits the 170/wave budget at
// 3 waves/SIMD -> no spill). template<NSEG> removes o1p + runtime branches
// from the split instantiation. NSEG==3: sid 0=pool, 1=SA[0,64), 2=SA[64,128),
// grid 768 = 3 blocks/CU exact. NSEG==1: monolithic fallback.
template <int NSEG>
__global__ __launch_bounds__(256, 3) void attn_kernel(
    const u16* __restrict__ q_t, const u16* __restrict__ k_t,
    const u16* __restrict__ pool_k, const u16* __restrict__ pool_vt,
    const u16* __restrict__ gvt, u16* __restrict__ feat1,
    u16* __restrict__ parts, float* __restrict__ lse) {
  __shared__ __align__(16) char smem[32768];   // K dbuf 16K | V dbuf 16K
  char* kB = smem;
  char* vB = smem + 16384;

  const int tid = threadIdx.x;
  const int w = tid >> 6, lane = tid & 63, lo = lane & 15, hi = lane >> 4;
  const int b = blockIdx.x & 7;
  const int nt = (blockIdx.x >> 3) & 31;
  const int sid = (int)(blockIdx.x >> 8);    // 0..2 (0 when NSEG==1)
  const int n0 = nt * 128;
  const int tcnt = (NSEG == 3) ? 64 : 192;

  const int k_dr = lane >> 4, k_cb = (lane & 15) * 16;
  const int sw = (lo & 7) << 4;

  const char* ktb = (const char*)(k_t + (size_t)b * N_ * FD_);
  const char* vtb = (const char*)(gvt + (size_t)b * 128 * 4096);
  const char* kseg0;
  const char* vseg0;
  const char* kseg1;
  const char* vseg1;
  if (NSEG == 3) {
    if (sid == 0) { kseg0 = (const char*)pool_k; vseg0 = (const char*)pool_vt; }
    else { kseg0 = ktb + (size_t)(sid - 1) * 524288; vseg0 = vtb + (size_t)(sid - 1) * 524288; }
    kseg1 = kseg0 + 524288; vseg1 = vseg0 + 524288;  // unused (tcnt<=64)
  } else {
    kseg0 = (const char*)pool_k; vseg0 = (const char*)pool_vt;
    kseg1 = ktb; vseg1 = vtb;
  }

  // Q fragments (theta, pre-scaled by LOG2E): wave w owns q rows n0+w*32..+31
  s16x8 q[2][4];
#pragma unroll
  for (int qf = 0; qf < 2; ++qf) {
    const u16* qbase = q_t + (size_t)(b * N_ + n0 + w * 32 + qf * 16 + lo) * FD_;
#pragma unroll
    for (int kk = 0; kk < 4; ++kk) q[qf][kk] = *(const s16x8*)(qbase + kk * 32 + hi * 8);
  }

  float m_r = -__builtin_inff();
  float l_r[2] = {0.f, 0.f};
  f32x4 o[2][8];
  u32 o1p[2][8][2];   // only live in the NSEG==1 instantiation
#pragma unroll
  for (int qf = 0; qf < 2; ++qf)
#pragma unroll
    for (int ft = 0; ft < 8; ++ft) {
#pragma unroll
      for (int j = 0; j < 4; ++j) o[qf][ft][j] = 0.f;
      if (NSEG == 1) { o1p[qf][ft][0] = 0u; o1p[qf][ft][1] = 0u; }
    }

#define STAGE(i, bufsel)                                                   \
  {                                                                        \
    const char* kg = ((i) < 64) ? kseg0 + (size_t)(i)*8192                 \
                                : kseg1 + (size_t)((i)-64) * 8192;         \
    const char* vg = ((i) < 64) ? vseg0 + (size_t)(i)*8192                 \
                                : vseg1 + (size_t)((i)-64) * 8192;         \
    char* kl = kB + (bufsel)*8192;                                         \
    char* vl = vB + (bufsel)*8192;                                         \
    _Pragma("unroll") for (int cc2 = 0; cc2 < 2; ++cc2) {                  \
      int c = w * 2 + cc2;                                                 \
      int rl = c * 4 + k_dr;                                               \
      gl16(kg + rl * 256 + (k_cb ^ ((rl & 7) << 4)), kl + c * 1024);       \
      gl16(vg + c * 1024 + lane * 16, vl + c * 1024);                      \
    }                                                                      \
  }

  STAGE(0, 0);
  __syncthreads();

  int buf = 0;
  for (int i = 0; i < tcnt; ++i) {
    if (i + 1 < tcnt) STAGE(i + 1, buf ^ 1);
    if (NSEG == 1 && i == 64) {   // finalize pool phase (monolithic only)
#pragma unroll
      for (int qf = 0; qf < 2; ++qf) {
        float lq = l_r[qf];
        lq += __shfl_xor(lq, 16);
        lq += __shfl_xor(lq, 32);
        float inv = __builtin_amdgcn_rcpf(lq);
#pragma unroll
        for (int ft = 0; ft < 8; ++ft) {
          o1p[qf][ft][0] = pkbf(o[qf][ft][0] * inv, o[qf][ft][1] * inv);
          o1p[qf][ft][1] = pkbf(o[qf][ft][2] * inv, o[qf][ft][3] * inv);
#pragma unroll
          for (int j = 0; j < 4; ++j) o[qf][ft][j] = 0.f;
        }
        l_r[qf] = 0.f;
      }
      m_r = -__builtin_inff();
    }

    const char* kbc = kB + buf * 8192;
    const char* vbc = vB + buf * 8192;

    // S^T = mfma(K, Q)
    f32x4 s[2][2];
#pragma unroll
    for (int qf = 0; qf < 2; ++qf)
#pragma unroll
      for (int t = 0; t < 2; ++t)
#pragma unroll
        for (int j = 0; j < 4; ++j) s[qf][t][j] = 0.f;
#pragma unroll
    for (int kk = 0; kk < 4; ++kk) {
      const int cb = (kk * 64 + hi * 16) ^ sw;
      s16x8 kf0 = *(const s16x8*)(kbc + lo * 256 + cb);
      s16x8 kf1 = *(const s16x8*)(kbc + (16 + lo) * 256 + cb);
#pragma unroll
      for (int qf = 0; qf < 2; ++qf) {
        s[qf][0] = __builtin_amdgcn_mfma_f32_16x16x32_bf16(kf0, q[qf][kk], s[qf][0], 0, 0, 0);
        s[qf][1] = __builtin_amdgcn_mfma_f32_16x16x32_bf16(kf1, q[qf][kk], s[qf][1], 0, 0, 0);
      }
    }
    // lane-max check; wave max + rescale only in the rare branch (defer-max)
    float lm = fmaxf(
        fmaxf(fmaxf(fmaxf(s[0][0][0], s[0][0][1]), fmaxf(s[0][0][2], s[0][0][3])),
              fmaxf(fmaxf(s[0][1][0], s[0][1][1]), fmaxf(s[0][1][2], s[0][1][3]))),
        fmaxf(fmaxf(fmaxf(s[1][0][0], s[1][0][1]), fmaxf(s[1][0][2], s[1][0][3])),
              fmaxf(fmaxf(s[1][1][0], s[1][1][1]), fmaxf(s[1][1][2], s[1][1][3]))));
    if (__any(lm - m_r > 11.5f)) {
      float tm = fmaxf(lm, __shfl_xor(lm, 16));
      tm = fmaxf(tm, __shfl_xor(tm, 32));
      float mn = fmaxf(m_r, tm);
      float al = exp2f(m_r - mn);
      m_r = mn;
      l_r[0] *= al;
      l_r[1] *= al;
#pragma unroll
      for (int qf = 0; qf < 2; ++qf)
#pragma unroll
        for (int ft = 0; ft < 8; ++ft)
#pragma unroll
          for (int j = 0; j < 4; ++j) o[qf][ft][j] *= al;
    }
    // P = exp2(S - m); partial row sums; pack directly to PV B-frags
    union Frag { u32 u[4]; s16x8 v; };
    Frag pb[2];
#pragma unroll
    for (int qf = 0; qf < 2; ++qf) {
      float rs = 0.f;
#pragma unroll
      for (int t = 0; t < 2; ++t)
#pragma unroll
        for (int j = 0; j < 4; ++j) {
          float p = exp2f(s[qf][t][j] - m_r);
          s[qf][t][j] = p;
          rs += p;
        }
      l_r[qf] += rs;
      pb[qf].u[0] = pkbf(s[qf][0][0], s[qf][0][1]);
      pb[qf].u[1] = pkbf(s[qf][0][2], s[qf][0][3]);
      pb[qf].u[2] = pkbf(s[qf][1][0], s[qf][1][1]);
      pb[qf].u[3] = pkbf(s[qf][1][2], s[qf][1][3]);
    }
    // PV
#pragma unroll
    for (int ft = 0; ft < 8; ++ft) {
      const int f = ft * 16 + lo;
      s16x8 vf = *(const s16x8*)(vbc + hi * 2048 + f * 16);
      o[0][ft] = __builtin_amdgcn_mfma_f32_16x16x32_bf16(vf, pb[0].v, o[0][ft], 0, 0, 0);
      o[1][ft] = __builtin_amdgcn_mfma_f32_16x16x32_bf16(vf, pb[1].v, o[1][ft], 0, 0, 0);
    }
    __syncthreads();   // drains prefetch + protects buf swap
    buf ^= 1;
  }
#undef STAGE

  // epilogue
#pragma unroll
  for (int qf = 0; qf < 2; ++qf) {
    float lq = l_r[qf];
    lq += __shfl_xor(lq, 16);
    lq += __shfl_xor(lq, 32);
    float inv = __builtin_amdgcn_rcpf(lq);
    const size_t row = (size_t)(b * N_ + n0 + w * 32 + qf * 16 + lo);
    if (NSEG == 1) {
#pragma unroll
      for (int ft = 0; ft < 8; ++ft) {
        float v0 = lo16(o1p[qf][ft][0]) + o[qf][ft][0] * inv;
        float v1 = hi16(o1p[qf][ft][0]) + o[qf][ft][1] * inv;
        float v2 = lo16(o1p[qf][ft][1]) + o[qf][ft][2] * inv;
        float v3 = hi16(o1p[qf][ft][1]) + o[qf][ft][3] * inv;
        uint2 st = {pkbf(v0, v1), pkbf(v2, v3)};
        *(uint2*)(feat1 + row * FD_ + ft * 16 + hi * 4) = st;
      }
    } else {
      u16* dst = parts + (size_t)sid * 4194304;
#pragma unroll
      for (int ft = 0; ft < 8; ++ft) {
        uint2 st = {pkbf(o[qf][ft][0] * inv, o[qf][ft][1] * inv),
                    pkbf(o[qf][ft][2] * inv, o[qf][ft][3] * inv)};
        *(uint2*)(dst + row * FD_ + ft * 16 + hi * 4) = st;
      }
      if (sid > 0 && hi == 0) lse[(sid - 1) * 32768 + row] = m_r + log2f(lq);
    }
  }
}

// ============================ merge3: featq = parts0 + combine(parts1,2) ====
__global__ __launch_bounds__(256) void merge3_kernel(
    const u16* __restrict__ parts, const float* __restrict__ lse,
    u16* __restrict__ featq) {
  const int tid = threadIdx.x;
  const int n = blockIdx.x * 32 + (tid >> 3);
  const int fc = (tid & 7) * 16;
  float l1 = lse[n], l2 = lse[32768 + n];
  float mx = fmaxf(l1, l2);
  float w1 = exp2f(l1 - mx), w2 = exp2f(l2 - mx);
  float dn = __builtin_amdgcn_rcpf(w1 + w2);
  float a1 = w1 * dn, a2 = w2 * dn;
  const size_t base = (size_t)n * FD_ + fc;
#pragma unroll
  for (int h = 0; h < 2; ++h) {
    s16x8 xp = *(const s16x8*)(parts + base + h * 8);
    s16x8 x1 = *(const s16x8*)(parts + 4194304 + base + h * 8);
    s16x8 x2 = *(const s16x8*)(parts + 8388608 + base + h * 8);
    s16x8 r;
#pragma unroll
    for (int i = 0; i < 8; ++i) {
      float v = bf2f((u16)xp[i]) + bf2f((u16)x1[i]) * a1 + bf2f((u16)x2[i]) * a2;
      r[i] = (short)f2bf(v);
    }
    *(s16x8*)(featq + base + h * 8) = r;
  }
}

// ============================ final: out = gamma * (w_o @ feat) + x =========
__global__ __launch_bounds__(256) void final_kernel(
    const float* __restrict__ x, const u16* __restrict__ wo_bf,
    const u16* __restrict__ feat, const float* __restrict__ gamma,
    float* __restrict__ out) {
  __shared__ __align__(16) char sm[17408];   // stage 16K; epilogue fl aliases
  float* fl = (float*)sm;
  const int tid = threadIdx.x;
  const int w = tid >> 6, lane = tid & 63, lo = lane & 15, hi = lane >> 4;
  const int n0 = blockIdx.x * 64, c0 = blockIdx.y * 64, b = blockIdx.z;

  // stage feat tile [64 n][128 f] (16KB), source pre-swizzled
  {
    const char* fb = (const char*)(feat + (size_t)(b * N_ + n0) * FD_);
#pragma unroll
    for (int r2 = 0; r2 < 4; ++r2) {
      int off = r2 * 4096 + tid * 16;
      int row = off >> 8, colb = off & 255;
      gl16(fb + row * 256 + (colb ^ ((row & 7) << 4)), sm + off);
    }
  }
  // prefetch wo fragments
  const u16* arow = wo_bf + (c0 + w * 16 + lo) * FD_ + hi * 8;
  s16x8 af[4];
#pragma unroll
  for (int kk = 0; kk < 4; ++kk) af[kk] = *(const s16x8*)(arow + kk * 32);

  f32x4 acc[4];
#pragma unroll
  for (int i = 0; i < 4; ++i)
#pragma unroll
    for (int j = 0; j < 4; ++j) acc[i][j] = 0.f;

  __syncthreads();   // staging complete

  const int swf = (lo & 7) << 4;
#pragma unroll
  for (int kk = 0; kk < 4; ++kk)
#pragma unroll
    for (int nt = 0; nt < 4; ++nt) {
      const int row = nt * 16 + lo;
      s16x8 bf = *(const s16x8*)(sm + row * 256 + ((kk * 64 + hi * 16) ^ swf));
      acc[nt] = __builtin_amdgcn_mfma_f32_16x16x32_bf16(af[kk], bf, acc[nt], 0, 0, 0);
    }

  __syncthreads();   // LDS reads done before fl overwrite
#pragma unroll
  for (int nt = 0; nt < 4; ++nt)
#pragma unroll
    for (int j = 0; j < 4; ++j)
      fl[(w * 16 + hi * 4 + j) * 68 + nt * 16 + lo] = acc[nt][j];
  __syncthreads();
  const float gm = gamma[0];
  const int cl = tid >> 2, nc = (tid & 3) * 16;
  const size_t xo = (size_t)b * C_ * N_ + (size_t)(c0 + cl) * N_ + n0 + nc;
  const float* sp = fl + cl * 68 + nc;
#pragma unroll
  for (int k2 = 0; k2 < 4; ++k2) {
    float4 v = *(const float4*)(sp + k2 * 4);
    float4 xi = *(const float4*)(x + xo + k2 * 4);
    float4 r;
    r.x = gm * v.x + xi.x;
    r.y = gm * v.y + xi.y;
    r.z = gm * v.z + xi.z;
    r.w = gm * v.w + xi.w;
    *(float4*)(out + xo + k2 * 4) = r;
  }
}

// ============================ launch =======================================
extern "C" void kernel_launch(void* const* d_in, const int* in_sizes, int n_in,
                              void* d_out, int out_size, void* d_ws, size_t ws_size,
                              hipStream_t stream) {
  const float* x = (const float*)d_in[0];
  const float* wth = (const float*)d_in[1];
  const float* wph = (const float*)d_in[2];
  const float* wg = (const float*)d_in[3];
  const float* wo = (const float*)d_in[4];
  const float* gamma = (const float*)d_in[5];
  const float* pool = (const float*)d_in[6];
  float* out = (float*)d_out;

  char* ws = (char*)d_ws;
  u16* wcat    = (u16*)(ws + 0);          //  384*1024*2 = 786432
  u16* wo_bf   = (u16*)(ws + 786432);     // 1024*128*2  = 262144
  u16* pool_k  = (u16*)(ws + 1048576);    // 2048*128*2  = 524288
  u16* pool_vt = (u16*)(ws + 1572864);    //  64*4*128*8*2 = 524288
  u16* q_t     = (u16*)(ws + 2097152);    // 8*4096*128*2 = 8388608
  u16* k_t     = (u16*)(ws + 10485760);   // 8*4096*128*2 = 8388608
  u16* gvt     = (u16*)(ws + 18874368);   // 8*128*4*128*8*2 = 8388608
  u16* parts   = (u16*)(ws + 27262976);   // 3 slots x 8388608
  u16* feat1   = (u16*)(ws + 27262976);   // NSEG==1 feat dest (aliases slot0)
  float* lse   = (float*)(ws + 52428800); // 2*32768*4 = 262144
  u16* featq   = q_t;                     // merged feat (q_t dead after attn)

  const size_t NEED3 = 52690944ull;       // 3 slots + 2*32768*4 lse
  const int NSEG = (ws_size >= NEED3) ? 3 : 1;

  prep_kernel<<<4096, 256, 0, stream>>>(wth, wph, wg, wo, pool, wcat, wo_bf, pool_k, pool_vt);
  proj_kernel<<<768, 256, 0, stream>>>(x, wcat, q_t, k_t, gvt);
  const u16* featp;
  if (NSEG == 3) {
    attn_kernel<3><<<768, 256, 0, stream>>>(q_t, k_t, pool_k, pool_vt, gvt,
                                            feat1, parts, lse);
    merge3_kernel<<<1024, 256, 0, stream>>>(parts, lse, featq);
    featp = featq;
  } else {
    attn_kernel<1><<<256, 256, 0, stream>>>(q_t, k_t, pool_k, pool_vt, gvt,
                                            feat1, parts, lse);
    featp = feat1;
  }
  final_kernel<<<dim3(64, 16, 8), 256, 0, stream>>>(x, wo_bf, featp, gamma, out);
}